// Round 2
// baseline (414.632 us; speedup 1.0000x reference)
//
#include <hip/hip_runtime.h>

// Problem constants (from reference): H=256, N=100000, B=8, S=128 -> T=1024
#define T_ROWS 1024
#define H_DIM  256
#define N_COLS 100000
#define BN     64
#define NTILES (N_COLS / BN + 1)       // 1563 (last tile partial)
#define TTILES (T_ROWS / 64)           // 16
#define QF     127.0f

typedef __attribute__((ext_vector_type(4))) float f32x4;
typedef __attribute__((ext_vector_type(8))) short short8;   // 8 bf16 = 4 VGPRs (MFMA A/B frag)
typedef __attribute__((ext_vector_type(4))) short short4v;  // 4 bf16 = 8B

__device__ __forceinline__ float wave_absmax(float v) {
#pragma unroll
    for (int off = 32; off > 0; off >>= 1)
        v = fmaxf(v, __shfl_xor(v, off, 64));
    return v;
}

// Exact f32 -> bf16 for integer-valued floats |q| <= 127 (7 significant bits
// fit bf16's 8-bit significand): plain truncation of the top 16 bits is exact.
__device__ __forceinline__ short f32_to_bf16_exact(float f) {
    unsigned u = __builtin_bit_cast(unsigned, f);
    return (short)(u >> 16);
}

// ---------------- Kernel 1: per-row quantize X -> integer-valued bf16 + absmax
__global__ __launch_bounds__(256) void quant_x(const float* __restrict__ X,
                                               short* __restrict__ x8,
                                               float* __restrict__ sx) {
    const int w = threadIdx.x >> 6, l = threadIdx.x & 63;
    const int row = blockIdx.x * 4 + w;            // wave per row, 4 rows/block
    const float4 v = ((const float4*)X)[row * 64 + l];   // coalesced 16B/lane
    float amax = fmaxf(fmaxf(fabsf(v.x), fabsf(v.y)), fmaxf(fabsf(v.z), fabsf(v.w)));
    amax = wave_absmax(amax);
    const float scale = (amax == 0.f) ? 1.f : amax;
    const float qs = QF / scale;                   // matches ref: x * (127/scale)
    short4v q;
    q.x = f32_to_bf16_exact(rintf(v.x * qs));      // rintf == jnp.rint (RNE)
    q.y = f32_to_bf16_exact(rintf(v.y * qs));
    q.z = f32_to_bf16_exact(rintf(v.z * qs));
    q.w = f32_to_bf16_exact(rintf(v.w * qs));
    *(short4v*)(x8 + row * H_DIM + l * 4) = q;     // plain row-major [1024][256]
    if (l == 0) sx[row] = amax;
}

// ---------------- Kernel 2: per-row quantize W -> integer-valued bf16 + absmax
// Pure streaming: read 102.4 MB f32, write 51.2 MB bf16. 25000 blocks.
__global__ __launch_bounds__(256) void quant_w(const float* __restrict__ W,
                                               short* __restrict__ w8,
                                               float* __restrict__ sw) {
    const int w = threadIdx.x >> 6, l = threadIdx.x & 63;
    const int row = blockIdx.x * 4 + w;            // N=100000 = 25000*4 exactly
    const float4 v = ((const float4*)W)[(size_t)row * 64 + l];
    float amax = fmaxf(fmaxf(fabsf(v.x), fabsf(v.y)), fmaxf(fabsf(v.z), fabsf(v.w)));
    amax = wave_absmax(amax);
    const float scale = (amax == 0.f) ? 1.f : amax;
    const float qs = QF / scale;
    short4v q;
    q.x = f32_to_bf16_exact(rintf(v.x * qs));
    q.y = f32_to_bf16_exact(rintf(v.y * qs));
    q.z = f32_to_bf16_exact(rintf(v.z * qs));
    q.w = f32_to_bf16_exact(rintf(v.w * qs));
    *(short4v*)(w8 + (size_t)row * H_DIM + l * 4) = q;
    if (l == 0) sw[row] = amax;
}

// ---------------- Kernel 3: barrier-free, LDS-free tiled GEMM + dequant
// Grid: 16 T-tiles x 1563 N-tiles = 25008 blocks (%8==0 -> bijective XCD
// swizzle). tt-inner ordering: the 16 blocks sharing an n-panel run
// back-to-back on one XCD -> w8 panel (32KB) reused 16x from L2.
// All fragments read directly from L2/L3-resident x8/w8 (no LDS, no
// __syncthreads) -> occupancy limited only by VGPRs, deep TLP hides latency.
__global__ __launch_bounds__(256, 4) void gemm_tiled(const short* __restrict__ x8,
                                                     const float* __restrict__ sx,
                                                     const short* __restrict__ w8,
                                                     const float* __restrict__ sw,
                                                     const float* __restrict__ bias,
                                                     float* __restrict__ out) {
    // bijective XCD swizzle: 25008 = 8 * 3126
    const int bid = blockIdx.x;
    const int s = (bid & 7) * 3126 + (bid >> 3);
    const int ntile = s >> 4;                 // 0..1562
    const int tt = s & 15;                    // 0..15 (inner -> L2 reuse of w8)
    const int n0 = ntile * BN;
    const int t0 = tt * 64;

    const int w = threadIdx.x >> 6, l = threadIdx.x & 63;
    const int wm = w >> 1, wn = w & 1;        // 2m x 2n wave grid (64x64 tile)
    const int lg = l >> 4, lm = l & 15;

    // per-lane column constants (clamp row for the one partial n-tile)
    int   ncol[2], brow[2];
    float swv[2], bv[2];
#pragma unroll
    for (int nr = 0; nr < 2; ++nr) {
        ncol[nr] = n0 + wn * 32 + nr * 16 + lm;
        brow[nr] = ncol[nr] < N_COLS ? ncol[nr] : N_COLS - 1;
        swv[nr] = sw[brow[nr]];
        bv[nr]  = bias[brow[nr]];
    }

    // hoist sx (on the store critical path) ahead of the MFMA loop
    float sxv[2][4];
#pragma unroll
    for (int mr = 0; mr < 2; ++mr)
#pragma unroll
        for (int r = 0; r < 4; ++r)
            sxv[mr][r] = sx[t0 + wm * 32 + mr * 16 + lg * 4 + r];

    const short* Abase = x8 + (t0 + wm * 32 + lm) * H_DIM + 8 * lg;
    const short* B0 = w8 + (size_t)brow[0] * H_DIM + 8 * lg;
    const short* B1 = w8 + (size_t)brow[1] * H_DIM + 8 * lg;

    const f32x4 zero4 = {0.f, 0.f, 0.f, 0.f};
    f32x4 acc[2][2];
    acc[0][0] = zero4; acc[0][1] = zero4; acc[1][0] = zero4; acc[1][1] = zero4;

#pragma unroll
    for (int kk = 0; kk < 8; ++kk) {
        const short8 a0 = *(const short8*)(Abase + kk * 32);
        const short8 a1 = *(const short8*)(Abase + 16 * H_DIM + kk * 32);
        const short8 b0 = *(const short8*)(B0 + kk * 32);
        const short8 b1 = *(const short8*)(B1 + kk * 32);
        acc[0][0] = __builtin_amdgcn_mfma_f32_16x16x32_bf16(a0, b0, acc[0][0], 0, 0, 0);
        acc[0][1] = __builtin_amdgcn_mfma_f32_16x16x32_bf16(a0, b1, acc[0][1], 0, 0, 0);
        acc[1][0] = __builtin_amdgcn_mfma_f32_16x16x32_bf16(a1, b0, acc[1][0], 0, 0, 0);
        acc[1][1] = __builtin_amdgcn_mfma_f32_16x16x32_bf16(a1, b1, acc[1][1], 0, 0, 0);
    }

    // epilogue: dequant + bias. C/D layout: col=lane&15, row=(lane>>4)*4+r.
    // Quarter-wave (16 lanes) stores 64B contiguous -> coalesced.
    const float invqq = 1.0f / (QF * QF);
#pragma unroll
    for (int mr = 0; mr < 2; ++mr) {
#pragma unroll
        for (int r = 0; r < 4; ++r) {
            const int t = t0 + wm * 32 + mr * 16 + lg * 4 + r;
            const float s0 = sxv[mr][r] * invqq;
#pragma unroll
            for (int nr = 0; nr < 2; ++nr) {
                if (ncol[nr] < N_COLS)
                    out[(size_t)t * N_COLS + ncol[nr]] =
                        acc[mr][nr][r] * (s0 * swv[nr]) + bv[nr];
            }
        }
    }
}

// ---------------- Fallback fused kernel (used only if ws too small for w8)
__global__ __launch_bounds__(256, 3) void gemm_main(const float* __restrict__ W,
                                                    const float* __restrict__ bias,
                                                    const short* __restrict__ x8,
                                                    const float* __restrict__ sx,
                                                    float* __restrict__ out) {
    __shared__ short wlds[BN * H_DIM];
    __shared__ float sw_lds[BN];

    const int tid = threadIdx.x;
    const int w = tid >> 6, l = tid & 63;
    const int n0 = blockIdx.x * BN;

    const float4* W4 = (const float4*)W;
#pragma unroll 4
    for (int r = 0; r < 16; ++r) {
        const int row = r * 4 + w;
        const int n = n0 + row;
        float4 v;
        if (n < N_COLS) v = W4[(size_t)n * 64 + l];
        else { v.x = 0.f; v.y = 0.f; v.z = 0.f; v.w = 0.f; }
        float amax = fmaxf(fmaxf(fabsf(v.x), fabsf(v.y)), fmaxf(fabsf(v.z), fabsf(v.w)));
        amax = wave_absmax(amax);
        const float scale = (amax == 0.f) ? 1.f : amax;
        const float qs = QF / scale;
        short4v q;
        q.x = f32_to_bf16_exact(rintf(v.x * qs));
        q.y = f32_to_bf16_exact(rintf(v.y * qs));
        q.z = f32_to_bf16_exact(rintf(v.z * qs));
        q.w = f32_to_bf16_exact(rintf(v.w * qs));
        const int sidx = row * H_DIM + ((l * 4) ^ ((row & 7) << 3));
        *(short4v*)(wlds + sidx) = q;
        if (l == 0) sw_lds[row] = amax;
    }
    __syncthreads();

    const int wm = w >> 1, wn = w & 1;
    const int lg = l >> 4, lm = l & 15;

    float swv[2], bv[2];
#pragma unroll
    for (int nr = 0; nr < 2; ++nr) {
        const int ncol = wn * 32 + nr * 16 + lm;
        swv[nr] = sw_lds[ncol];
        const int n = n0 + ncol;
        bv[nr] = (n < N_COLS) ? bias[n] : 0.f;
    }

    short8 bfr[2][8];
#pragma unroll
    for (int nr = 0; nr < 2; ++nr) {
        const int row = wn * 32 + nr * 16 + lm;
#pragma unroll
        for (int kk = 0; kk < 8; ++kk) {
            const int sidx = row * H_DIM + ((kk * 32 + 8 * lg) ^ ((row & 7) << 3));
            bfr[nr][kk] = *(const short8*)(wlds + sidx);
        }
    }

    const float invqq = 1.0f / (QF * QF);
    const f32x4 zero4 = {0.f, 0.f, 0.f, 0.f};

    for (int tt = 0; tt < 16; ++tt) {
        const int t0 = tt * 64;
        f32x4 acc[2][2];
        acc[0][0] = zero4; acc[0][1] = zero4; acc[1][0] = zero4; acc[1][1] = zero4;

        const short* abase0 = x8 + (t0 + wm * 32 + lm) * H_DIM + 8 * lg;
#pragma unroll
        for (int kk = 0; kk < 8; ++kk) {
            const short8 a0 = *(const short8*)(abase0 + kk * 32);
            const short8 a1 = *(const short8*)(abase0 + 16 * H_DIM + kk * 32);
            acc[0][0] = __builtin_amdgcn_mfma_f32_16x16x32_bf16(a0, bfr[0][kk], acc[0][0], 0, 0, 0);
            acc[0][1] = __builtin_amdgcn_mfma_f32_16x16x32_bf16(a0, bfr[1][kk], acc[0][1], 0, 0, 0);
            acc[1][0] = __builtin_amdgcn_mfma_f32_16x16x32_bf16(a1, bfr[0][kk], acc[1][0], 0, 0, 0);
            acc[1][1] = __builtin_amdgcn_mfma_f32_16x16x32_bf16(a1, bfr[1][kk], acc[1][1], 0, 0, 0);
        }

#pragma unroll
        for (int mr = 0; mr < 2; ++mr) {
            const int trow = t0 + wm * 32 + mr * 16 + lg * 4;
#pragma unroll
            for (int r = 0; r < 4; ++r) {
                const int t = trow + r;
                const float sxv = sx[t];
#pragma unroll
                for (int nr = 0; nr < 2; ++nr) {
                    const int n = n0 + wn * 32 + nr * 16 + lm;
                    if (n < N_COLS)
                        out[(size_t)t * N_COLS + n] =
                            acc[mr][nr][r] * ((sxv * swv[nr]) * invqq) + bv[nr];
                }
            }
        }
    }
}

extern "C" void kernel_launch(void* const* d_in, const int* in_sizes, int n_in,
                              void* d_out, int out_size, void* d_ws, size_t ws_size,
                              hipStream_t stream) {
    const float* X    = (const float*)d_in[0];   // [8,128,256] f32
    const float* W    = (const float*)d_in[1];   // [100000,256] f32
    const float* bias = (const float*)d_in[2];   // [100000] f32
    float* out = (float*)d_out;                  // [1024,100000] f32

    // ws layout: x8 [1024*256 bf16] | sx [1024 f32] | w8 [100000*256 bf16] | sw [100000 f32]
    const size_t x8_bytes = (size_t)T_ROWS * H_DIM * 2;       // 524288
    const size_t sx_bytes = (size_t)T_ROWS * 4;               // 4096
    const size_t w8_bytes = (size_t)N_COLS * H_DIM * 2;       // 51,200,000
    const size_t sw_bytes = (size_t)N_COLS * 4;               // 400,000
    const size_t need = x8_bytes + sx_bytes + w8_bytes + sw_bytes;

    short* x8 = (short*)d_ws;
    float* sx = (float*)((char*)d_ws + x8_bytes);

    quant_x<<<T_ROWS / 4, 256, 0, stream>>>(X, x8, sx);

    if (ws_size >= need) {
        short* w8 = (short*)((char*)d_ws + x8_bytes + sx_bytes);
        float* sw = (float*)((char*)d_ws + x8_bytes + sx_bytes + w8_bytes);
        quant_w<<<N_COLS / 4, 256, 0, stream>>>(W, w8, sw);
        gemm_tiled<<<TTILES * NTILES, 256, 0, stream>>>(x8, sx, w8, sw, bias, out);
    } else {
        gemm_main<<<NTILES, 256, 0, stream>>>(W, bias, x8, sx, out);
    }
}

// Round 3
// 332.155 us; speedup vs baseline: 1.2483x; 1.2483x over previous
//
#include <hip/hip_runtime.h>

// Problem constants (from reference): H=256, N=100000, B=8, S=128 -> T=1024
#define T_ROWS 1024
#define H_DIM  256
#define N_COLS 100000
#define QF     127.0f

// wide-tile gemm geometry
#define BM2 32
#define BN2 256
#define NT2 391            // ceil(100000/256), last panel 160 cols
#define TT2 (T_ROWS / BM2) // 32
#define GRID2 (NT2 * TT2)  // 12512 = 8 * 1564 -> bijective XCD swizzle

typedef __attribute__((ext_vector_type(4))) float f32x4;
typedef __attribute__((ext_vector_type(8))) short short8;   // 8 bf16 = 4 VGPRs (MFMA A/B frag)
typedef __attribute__((ext_vector_type(4))) short short4v;  // 4 bf16 = 8B

__device__ __forceinline__ float wave_absmax(float v) {
#pragma unroll
    for (int off = 32; off > 0; off >>= 1)
        v = fmaxf(v, __shfl_xor(v, off, 64));
    return v;
}

// Exact f32 -> bf16 for integer-valued floats |q| <= 127 (7 significant bits
// fit bf16's 8-bit significand): plain truncation of the top 16 bits is exact.
__device__ __forceinline__ short f32_to_bf16_exact(float f) {
    unsigned u = __builtin_bit_cast(unsigned, f);
    return (short)(u >> 16);
}

// ---------------- Kernel 1: per-row quantize X -> integer-valued bf16 + absmax
__global__ __launch_bounds__(256) void quant_x(const float* __restrict__ X,
                                               short* __restrict__ x8,
                                               float* __restrict__ sx) {
    const int w = threadIdx.x >> 6, l = threadIdx.x & 63;
    const int row = blockIdx.x * 4 + w;            // wave per row, 4 rows/block
    const float4 v = ((const float4*)X)[row * 64 + l];   // coalesced 16B/lane
    float amax = fmaxf(fmaxf(fabsf(v.x), fabsf(v.y)), fmaxf(fabsf(v.z), fabsf(v.w)));
    amax = wave_absmax(amax);
    const float scale = (amax == 0.f) ? 1.f : amax;
    const float qs = QF / scale;                   // matches ref: x * (127/scale)
    short4v q;
    q.x = f32_to_bf16_exact(rintf(v.x * qs));      // rintf == jnp.rint (RNE)
    q.y = f32_to_bf16_exact(rintf(v.y * qs));
    q.z = f32_to_bf16_exact(rintf(v.z * qs));
    q.w = f32_to_bf16_exact(rintf(v.w * qs));
    *(short4v*)(x8 + row * H_DIM + l * 4) = q;     // plain row-major [1024][256]
    if (l == 0) sx[row] = amax;
}

// ---------------- Kernel 2: per-row quantize W -> integer-valued bf16 + absmax
__global__ __launch_bounds__(256) void quant_w(const float* __restrict__ W,
                                               short* __restrict__ w8,
                                               float* __restrict__ sw) {
    const int w = threadIdx.x >> 6, l = threadIdx.x & 63;
    const int row = blockIdx.x * 4 + w;            // N=100000 = 25000*4 exactly
    const float4 v = ((const float4*)W)[(size_t)row * 64 + l];
    float amax = fmaxf(fmaxf(fabsf(v.x), fabsf(v.y)), fmaxf(fabsf(v.z), fabsf(v.w)));
    amax = wave_absmax(amax);
    const float scale = (amax == 0.f) ? 1.f : amax;
    const float qs = QF / scale;
    short4v q;
    q.x = f32_to_bf16_exact(rintf(v.x * qs));
    q.y = f32_to_bf16_exact(rintf(v.y * qs));
    q.z = f32_to_bf16_exact(rintf(v.z * qs));
    q.w = f32_to_bf16_exact(rintf(v.w * qs));
    *(short4v*)(w8 + (size_t)row * H_DIM + l * 4) = q;
    if (l == 0) sw[row] = amax;
}

// ---------------- Kernel 3: wide-tile GEMM, LDS-transposed coalesced epilogue
// Block tile: 32 t x 256 n. 4 waves, each owning 32t x 64n during MFMA.
// Frags read directly from L2/L3-resident x8/w8 (no staging). tt-inner XCD
// swizzle -> the 128KB w8 panel is reused 32x from L2.
// Epilogue: raw acc -> 32KB LDS tile -> each wave stores 8 full 1KB rows as
// wave-wide contiguous float4 stores (the experiment: long HBM write streams).
__global__ __launch_bounds__(256, 4) void gemm_wide(const short* __restrict__ x8,
                                                    const float* __restrict__ sx,
                                                    const short* __restrict__ w8,
                                                    const float* __restrict__ sw,
                                                    const float* __restrict__ bias,
                                                    float* __restrict__ out) {
    __shared__ float olds[BM2 * BN2];   // 32KB raw acc tile

    // bijective XCD swizzle (12512 = 8 * 1564), tt-inner for w8 L2 reuse
    const int bid = blockIdx.x;
    const int s = (bid & 7) * (GRID2 / 8) + (bid >> 3);
    const int ntile = s / TT2;            // 0..390
    const int tt = s % TT2;               // 0..31
    const int n0 = ntile * BN2;
    const int t0 = tt * BM2;

    const int w = threadIdx.x >> 6, l = threadIdx.x & 63;
    const int lg = l >> 4, lm = l & 15;

    // B row pointers for this wave's 64 n-cols (clamped for the partial panel)
    const short* Bbase[4];
#pragma unroll
    for (int nf = 0; nf < 4; ++nf) {
        int n = n0 + w * 64 + nf * 16 + lm;
        if (n >= N_COLS) n = N_COLS - 1;
        Bbase[nf] = w8 + (size_t)n * H_DIM + 8 * lg;
    }
    const short* Abase = x8 + (t0 + lm) * H_DIM + 8 * lg;

    const f32x4 zero4 = {0.f, 0.f, 0.f, 0.f};
    f32x4 acc[2][4];
#pragma unroll
    for (int mr = 0; mr < 2; ++mr)
#pragma unroll
        for (int nf = 0; nf < 4; ++nf) acc[mr][nf] = zero4;

#pragma unroll
    for (int kk = 0; kk < 8; ++kk) {
        const short8 a0 = *(const short8*)(Abase + kk * 32);
        const short8 a1 = *(const short8*)(Abase + 16 * H_DIM + kk * 32);
        short8 b[4];
#pragma unroll
        for (int nf = 0; nf < 4; ++nf) b[nf] = *(const short8*)(Bbase[nf] + kk * 32);
#pragma unroll
        for (int nf = 0; nf < 4; ++nf) {
            acc[0][nf] = __builtin_amdgcn_mfma_f32_16x16x32_bf16(a0, b[nf], acc[0][nf], 0, 0, 0);
            acc[1][nf] = __builtin_amdgcn_mfma_f32_16x16x32_bf16(a1, b[nf], acc[1][nf], 0, 0, 0);
        }
    }

    // raw acc -> LDS. C/D layout: col=lane&15, row=(lane>>4)*4+r.
    // ds_write_b32 4-way bank conflict here is negligible (m136: 1.58x on a tiny phase).
#pragma unroll
    for (int mr = 0; mr < 2; ++mr)
#pragma unroll
        for (int nf = 0; nf < 4; ++nf)
#pragma unroll
            for (int r = 0; r < 4; ++r)
                olds[(mr * 16 + lg * 4 + r) * BN2 + (w * 64 + nf * 16 + lm)] = acc[mr][nf][r];
    __syncthreads();

    // read back + dequant + contiguous stores: wave w stores rows 8w..8w+7,
    // each row = 64 lanes x float4 = 1KB contiguous.
    const float invqq = 1.0f / (QF * QF);
    const int ncol = n0 + l * 4;
    const bool ok = ncol < N_COLS;        // tail panel is 160 cols = 40 lanes
    float4 sw4 = {0.f, 0.f, 0.f, 0.f}, b4 = {0.f, 0.f, 0.f, 0.f};
    if (ok) {
        sw4 = *(const float4*)(sw + ncol);
        b4  = *(const float4*)(bias + ncol);
    }
#pragma unroll
    for (int i = 0; i < 8; ++i) {
        const int row = w * 8 + i;
        const int t = t0 + row;
        const float s0 = sx[t] * invqq;   // wave-uniform
        const f32x4 v = *(const f32x4*)(olds + row * BN2 + l * 4);
        if (ok) {
            float4 o;
            o.x = v[0] * (s0 * sw4.x) + b4.x;
            o.y = v[1] * (s0 * sw4.y) + b4.y;
            o.z = v[2] * (s0 * sw4.z) + b4.z;
            o.w = v[3] * (s0 * sw4.w) + b4.w;
            *(float4*)(out + (size_t)t * N_COLS + ncol) = o;
        }
    }
}

// ---------------- Fallback fused kernel (used only if ws too small for w8)
__global__ __launch_bounds__(256, 3) void gemm_main(const float* __restrict__ W,
                                                    const float* __restrict__ bias,
                                                    const short* __restrict__ x8,
                                                    const float* __restrict__ sx,
                                                    float* __restrict__ out) {
    __shared__ short wlds[64 * H_DIM];
    __shared__ float sw_lds[64];

    const int tid = threadIdx.x;
    const int w = tid >> 6, l = tid & 63;
    const int n0 = blockIdx.x * 64;

    const float4* W4 = (const float4*)W;
#pragma unroll 4
    for (int r = 0; r < 16; ++r) {
        const int row = r * 4 + w;
        const int n = n0 + row;
        float4 v;
        if (n < N_COLS) v = W4[(size_t)n * 64 + l];
        else { v.x = 0.f; v.y = 0.f; v.z = 0.f; v.w = 0.f; }
        float amax = fmaxf(fmaxf(fabsf(v.x), fabsf(v.y)), fmaxf(fabsf(v.z), fabsf(v.w)));
        amax = wave_absmax(amax);
        const float scale = (amax == 0.f) ? 1.f : amax;
        const float qs = QF / scale;
        short4v q;
        q.x = f32_to_bf16_exact(rintf(v.x * qs));
        q.y = f32_to_bf16_exact(rintf(v.y * qs));
        q.z = f32_to_bf16_exact(rintf(v.z * qs));
        q.w = f32_to_bf16_exact(rintf(v.w * qs));
        const int sidx = row * H_DIM + ((l * 4) ^ ((row & 7) << 3));
        *(short4v*)(wlds + sidx) = q;
        if (l == 0) sw_lds[row] = amax;
    }
    __syncthreads();

    const int wm = w >> 1, wn = w & 1;
    const int lg = l >> 4, lm = l & 15;

    float swv[2], bv[2];
#pragma unroll
    for (int nr = 0; nr < 2; ++nr) {
        const int ncol = wn * 32 + nr * 16 + lm;
        swv[nr] = sw_lds[ncol];
        const int n = n0 + ncol;
        bv[nr] = (n < N_COLS) ? bias[n] : 0.f;
    }

    short8 bfr[2][8];
#pragma unroll
    for (int nr = 0; nr < 2; ++nr) {
        const int row = wn * 32 + nr * 16 + lm;
#pragma unroll
        for (int kk = 0; kk < 8; ++kk) {
            const int sidx = row * H_DIM + ((kk * 32 + 8 * lg) ^ ((row & 7) << 3));
            bfr[nr][kk] = *(const short8*)(wlds + sidx);
        }
    }

    const float invqq = 1.0f / (QF * QF);
    const f32x4 zero4 = {0.f, 0.f, 0.f, 0.f};

    for (int tt = 0; tt < 16; ++tt) {
        const int t0 = tt * 64;
        f32x4 acc[2][2];
        acc[0][0] = zero4; acc[0][1] = zero4; acc[1][0] = zero4; acc[1][1] = zero4;

        const short* abase0 = x8 + (t0 + wm * 32 + lm) * H_DIM + 8 * lg;
#pragma unroll
        for (int kk = 0; kk < 8; ++kk) {
            const short8 a0 = *(const short8*)(abase0 + kk * 32);
            const short8 a1 = *(const short8*)(abase0 + 16 * H_DIM + kk * 32);
            acc[0][0] = __builtin_amdgcn_mfma_f32_16x16x32_bf16(a0, bfr[0][kk], acc[0][0], 0, 0, 0);
            acc[0][1] = __builtin_amdgcn_mfma_f32_16x16x32_bf16(a0, bfr[1][kk], acc[0][1], 0, 0, 0);
            acc[1][0] = __builtin_amdgcn_mfma_f32_16x16x32_bf16(a1, bfr[0][kk], acc[1][0], 0, 0, 0);
            acc[1][1] = __builtin_amdgcn_mfma_f32_16x16x32_bf16(a1, bfr[1][kk], acc[1][1], 0, 0, 0);
        }

#pragma unroll
        for (int mr = 0; mr < 2; ++mr) {
            const int trow = t0 + wm * 32 + mr * 16 + lg * 4;
#pragma unroll
            for (int r = 0; r < 4; ++r) {
                const int t = trow + r;
                const float sxv = sx[t];
#pragma unroll
                for (int nr = 0; nr < 2; ++nr) {
                    const int n = n0 + wn * 32 + nr * 16 + lm;
                    if (n < N_COLS)
                        out[(size_t)t * N_COLS + n] =
                            acc[mr][nr][r] * ((sxv * swv[nr]) * invqq) + bv[nr];
                }
            }
        }
    }
}

extern "C" void kernel_launch(void* const* d_in, const int* in_sizes, int n_in,
                              void* d_out, int out_size, void* d_ws, size_t ws_size,
                              hipStream_t stream) {
    const float* X    = (const float*)d_in[0];   // [8,128,256] f32
    const float* W    = (const float*)d_in[1];   // [100000,256] f32
    const float* bias = (const float*)d_in[2];   // [100000] f32
    float* out = (float*)d_out;                  // [1024,100000] f32

    // ws layout: x8 | sx | w8 | sw
    const size_t x8_bytes = (size_t)T_ROWS * H_DIM * 2;       // 524288
    const size_t sx_bytes = (size_t)T_ROWS * 4;               // 4096
    const size_t w8_bytes = (size_t)N_COLS * H_DIM * 2;       // 51,200,000
    const size_t sw_bytes = (size_t)N_COLS * 4;               // 400,000
    const size_t need = x8_bytes + sx_bytes + w8_bytes + sw_bytes;

    short* x8 = (short*)d_ws;
    float* sx = (float*)((char*)d_ws + x8_bytes);

    quant_x<<<T_ROWS / 4, 256, 0, stream>>>(X, x8, sx);

    if (ws_size >= need) {
        short* w8 = (short*)((char*)d_ws + x8_bytes + sx_bytes);
        float* sw = (float*)((char*)d_ws + x8_bytes + sx_bytes + w8_bytes);
        quant_w<<<N_COLS / 4, 256, 0, stream>>>(W, w8, sw);
        gemm_wide<<<GRID2, 256, 0, stream>>>(x8, sx, w8, sw, bias, out);
    } else {
        gemm_main<<<(N_COLS + 63) / 64, 256, 0, stream>>>(W, bias, x8, sx, out);
    }
}

// Round 4
// 264.423 us; speedup vs baseline: 1.5681x; 1.2561x over previous
//
#include <hip/hip_runtime.h>

// Problem constants (from reference): H=256, N=100000, B=8, S=128 -> T=1024
#define T_ROWS 1024
#define H_DIM  256
#define N_COLS 100000
#define QF     127.0f

// swapped-operand gemm geometry: block = 128 n x 256 t (8 iters of 32 t)
#define BNW   128                  // n per block (4 waves x 32)
#define NB3   782                  // ceil(100000/128), last block 32 cols
#define TCH   4                    // t-chunks of 256
#define GRID3 (NB3 * TCH)          // 3128 = 8*391 -> bijective XCD swizzle

typedef __attribute__((ext_vector_type(4))) float f32x4;
typedef __attribute__((ext_vector_type(8))) short short8;   // 8 bf16 (MFMA A/B frag)
typedef __attribute__((ext_vector_type(4))) short short4v;  // 4 bf16 = 8B

__device__ __forceinline__ float wave_absmax(float v) {
#pragma unroll
    for (int off = 32; off > 0; off >>= 1)
        v = fmaxf(v, __shfl_xor(v, off, 64));
    return v;
}

// Exact f32 -> bf16 for integer-valued floats |q| <= 127: truncation is exact.
__device__ __forceinline__ short f32_to_bf16_exact(float f) {
    unsigned u = __builtin_bit_cast(unsigned, f);
    return (short)(u >> 16);
}

// ---------------- Kernel 1: per-row quantize X -> integer-valued bf16 + absmax
__global__ __launch_bounds__(256) void quant_x(const float* __restrict__ X,
                                               short* __restrict__ x8,
                                               float* __restrict__ sx) {
    const int w = threadIdx.x >> 6, l = threadIdx.x & 63;
    const int row = blockIdx.x * 4 + w;
    const float4 v = ((const float4*)X)[row * 64 + l];
    float amax = fmaxf(fmaxf(fabsf(v.x), fabsf(v.y)), fmaxf(fabsf(v.z), fabsf(v.w)));
    amax = wave_absmax(amax);
    const float scale = (amax == 0.f) ? 1.f : amax;
    const float qs = QF / scale;
    short4v q;
    q.x = f32_to_bf16_exact(rintf(v.x * qs));
    q.y = f32_to_bf16_exact(rintf(v.y * qs));
    q.z = f32_to_bf16_exact(rintf(v.z * qs));
    q.w = f32_to_bf16_exact(rintf(v.w * qs));
    *(short4v*)(x8 + row * H_DIM + l * 4) = q;
    if (l == 0) sx[row] = amax;
}

// ---------------- Kernel 2: per-row quantize W -> integer-valued bf16 + absmax
__global__ __launch_bounds__(256) void quant_w(const float* __restrict__ W,
                                               short* __restrict__ w8,
                                               float* __restrict__ sw) {
    const int w = threadIdx.x >> 6, l = threadIdx.x & 63;
    const int row = blockIdx.x * 4 + w;            // N = 25000*4 exactly
    const float4 v = ((const float4*)W)[(size_t)row * 64 + l];
    float amax = fmaxf(fmaxf(fabsf(v.x), fabsf(v.y)), fmaxf(fabsf(v.z), fabsf(v.w)));
    amax = wave_absmax(amax);
    const float scale = (amax == 0.f) ? 1.f : amax;
    const float qs = QF / scale;
    short4v q;
    q.x = f32_to_bf16_exact(rintf(v.x * qs));
    q.y = f32_to_bf16_exact(rintf(v.y * qs));
    q.z = f32_to_bf16_exact(rintf(v.z * qs));
    q.w = f32_to_bf16_exact(rintf(v.w * qs));
    *(short4v*)(w8 + (size_t)row * H_DIM + l * 4) = q;
    if (l == 0) sw[row] = amax;
}

// ---------------- swapped-operand GEMM: no LDS, no barriers, store/compute overlap
// mfma(B-frag, A-frag) -> D[n][t]: col=lane&15 -> t, row=(lane>>4)*4+r -> n.
// Each lane's 4 acc regs = 4 CONSECUTIVE n at one t -> direct float4 store
// (4 lanes per lg-group form a 64B contiguous segment).
struct ABuf {
    short8 a[2][8];   // [mr][kk]
    float  sxv[2];    // sx for the two t-subtiles
};

__device__ __forceinline__ void load_a(ABuf& ab, const short* __restrict__ x8,
                                       const float* __restrict__ sx,
                                       int t0, int lm, int lg) {
#pragma unroll
    for (int mr = 0; mr < 2; ++mr) {
        const short* A = x8 + (t0 + mr * 16 + lm) * H_DIM + 8 * lg;
#pragma unroll
        for (int kk = 0; kk < 8; ++kk)
            ab.a[mr][kk] = *(const short8*)(A + kk * 32);
        ab.sxv[mr] = sx[t0 + mr * 16 + lm];
    }
}

__device__ __forceinline__ void mfma_tile(f32x4 (&acc)[2][2], const ABuf& ab,
                                          const short8 (&bfr)[2][8]) {
#pragma unroll
    for (int kk = 0; kk < 8; ++kk)
#pragma unroll
        for (int mr = 0; mr < 2; ++mr)
#pragma unroll
            for (int nf = 0; nf < 2; ++nf)
                acc[mr][nf] = __builtin_amdgcn_mfma_f32_16x16x32_bf16(
                    bfr[nf][kk], ab.a[mr][kk], acc[mr][nf], 0, 0, 0);
}

__device__ __forceinline__ void store_tile(const f32x4 (&acc)[2][2], const ABuf& ab,
                                           const f32x4 (&sw4)[2], const f32x4 (&b4)[2],
                                           const bool (&okn)[2],
                                           float* __restrict__ out,
                                           int t0, int lm, int lg, int nwave) {
    const float invqq = 1.0f / (QF * QF);
#pragma unroll
    for (int mr = 0; mr < 2; ++mr) {
        const int t = t0 + mr * 16 + lm;
        const float s0 = ab.sxv[mr] * invqq;
#pragma unroll
        for (int nf = 0; nf < 2; ++nf) {
            if (okn[nf]) {
                f32x4 o;
#pragma unroll
                for (int r = 0; r < 4; ++r)
                    o[r] = acc[mr][nf][r] * (s0 * sw4[nf][r]) + b4[nf][r];
                __builtin_nontemporal_store(
                    o, (f32x4*)(out + (size_t)t * N_COLS + nwave + nf * 16 + lg * 4));
            }
        }
    }
}

__global__ __launch_bounds__(256, 2) void gemm_swap(const short* __restrict__ x8,
                                                    const float* __restrict__ sx,
                                                    const short* __restrict__ w8,
                                                    const float* __restrict__ sw,
                                                    const float* __restrict__ bias,
                                                    float* __restrict__ out) {
    // bijective XCD swizzle (3128 = 8*391); tc-inner -> same XCD reuses its
    // w8 panel 4x from L2; each XCD owns a contiguous n-range.
    const int bid = blockIdx.x;
    const int s = (bid & 7) * (GRID3 / 8) + (bid >> 3);
    const int nb = s >> 2;                 // 0..781
    const int tc = s & 3;                  // t-chunk of 256 rows
    const int w = threadIdx.x >> 6, l = threadIdx.x & 63;
    const int lg = l >> 4, lm = l & 15;
    const int nwave = nb * BNW + w * 32;   // this wave's 32 n-columns
    const int tbase = tc * 256;

    // B-frags (persist in regs, reused across all 8 t-iters) + store-side scales
    short8 bfr[2][8];
    f32x4 sw4[2], b4[2];
    bool okn[2];
#pragma unroll
    for (int nf = 0; nf < 2; ++nf) {
        const int nrow = nwave + nf * 16 + lm;
        const int nc = nrow < N_COLS ? nrow : N_COLS - 1;
        const short* B = w8 + (size_t)nc * H_DIM + 8 * lg;
#pragma unroll
        for (int kk = 0; kk < 8; ++kk)
            bfr[nf][kk] = *(const short8*)(B + kk * 32);
        const int ns = nwave + nf * 16 + lg * 4;   // base n of this lane's float4
        okn[nf] = ns < N_COLS;                     // N%4==0 -> whole float4 in/out
        const int nsc = okn[nf] ? ns : 0;
        sw4[nf] = *(const f32x4*)(sw + nsc);
        b4[nf]  = *(const f32x4*)(bias + nsc);
    }

    ABuf a0, a1;
    load_a(a0, x8, sx, tbase, lm, lg);

    // 8 t-iterations, 2x-unrolled bodies with explicit double-buffer (rule #20:
    // static indexing only). Prefetch of iter i+1 is issued BEFORE stores of
    // iter i, so MFMA(i+1)'s vmcnt wait never waits on store completion.
#pragma unroll 1
    for (int ii = 0; ii < 4; ++ii) {
        const int t0 = tbase + ii * 64;
        {
            f32x4 acc[2][2];
#pragma unroll
            for (int mr = 0; mr < 2; ++mr)
#pragma unroll
                for (int nf = 0; nf < 2; ++nf) acc[mr][nf] = (f32x4){0.f, 0.f, 0.f, 0.f};
            mfma_tile(acc, a0, bfr);
            load_a(a1, x8, sx, t0 + 32, lm, lg);          // prefetch next
            store_tile(acc, a0, sw4, b4, okn, out, t0, lm, lg, nwave);
        }
        {
            f32x4 acc[2][2];
#pragma unroll
            for (int mr = 0; mr < 2; ++mr)
#pragma unroll
                for (int nf = 0; nf < 2; ++nf) acc[mr][nf] = (f32x4){0.f, 0.f, 0.f, 0.f};
            mfma_tile(acc, a1, bfr);
            if (ii < 3) load_a(a0, x8, sx, t0 + 64, lm, lg);  // prefetch next
            store_tile(acc, a1, sw4, b4, okn, out, t0 + 32, lm, lg, nwave);
        }
    }
}

// ---------------- Fallback fused kernel (used only if ws too small for w8)
__global__ __launch_bounds__(256, 3) void gemm_main(const float* __restrict__ W,
                                                    const float* __restrict__ bias,
                                                    const short* __restrict__ x8,
                                                    const float* __restrict__ sx,
                                                    float* __restrict__ out) {
    __shared__ short wlds[64 * H_DIM];
    __shared__ float sw_lds[64];

    const int tid = threadIdx.x;
    const int w = tid >> 6, l = tid & 63;
    const int n0 = blockIdx.x * 64;

    const float4* W4 = (const float4*)W;
#pragma unroll 4
    for (int r = 0; r < 16; ++r) {
        const int row = r * 4 + w;
        const int n = n0 + row;
        float4 v;
        if (n < N_COLS) v = W4[(size_t)n * 64 + l];
        else { v.x = 0.f; v.y = 0.f; v.z = 0.f; v.w = 0.f; }
        float amax = fmaxf(fmaxf(fabsf(v.x), fabsf(v.y)), fmaxf(fabsf(v.z), fabsf(v.w)));
        amax = wave_absmax(amax);
        const float scale = (amax == 0.f) ? 1.f : amax;
        const float qs = QF / scale;
        short4v q;
        q.x = f32_to_bf16_exact(rintf(v.x * qs));
        q.y = f32_to_bf16_exact(rintf(v.y * qs));
        q.z = f32_to_bf16_exact(rintf(v.z * qs));
        q.w = f32_to_bf16_exact(rintf(v.w * qs));
        const int sidx = row * H_DIM + ((l * 4) ^ ((row & 7) << 3));
        *(short4v*)(wlds + sidx) = q;
        if (l == 0) sw_lds[row] = amax;
    }
    __syncthreads();

    const int wm = w >> 1, wn = w & 1;
    const int lg = l >> 4, lm = l & 15;

    float swv[2], bv[2];
#pragma unroll
    for (int nr = 0; nr < 2; ++nr) {
        const int ncol = wn * 32 + nr * 16 + lm;
        swv[nr] = sw_lds[ncol];
        const int n = n0 + ncol;
        bv[nr] = (n < N_COLS) ? bias[n] : 0.f;
    }

    short8 bfr[2][8];
#pragma unroll
    for (int nr = 0; nr < 2; ++nr) {
        const int row = wn * 32 + nr * 16 + lm;
#pragma unroll
        for (int kk = 0; kk < 8; ++kk) {
            const int sidx = row * H_DIM + ((kk * 32 + 8 * lg) ^ ((row & 7) << 3));
            bfr[nr][kk] = *(const short8*)(wlds + sidx);
        }
    }

    const float invqq = 1.0f / (QF * QF);
    const f32x4 zero4 = {0.f, 0.f, 0.f, 0.f};

    for (int tt = 0; tt < 16; ++tt) {
        const int t0 = tt * 64;
        f32x4 acc[2][2];
        acc[0][0] = zero4; acc[0][1] = zero4; acc[1][0] = zero4; acc[1][1] = zero4;

        const short* abase0 = x8 + (t0 + wm * 32 + lm) * H_DIM + 8 * lg;
#pragma unroll
        for (int kk = 0; kk < 8; ++kk) {
            const short8 a0 = *(const short8*)(abase0 + kk * 32);
            const short8 a1 = *(const short8*)(abase0 + 16 * H_DIM + kk * 32);
            acc[0][0] = __builtin_amdgcn_mfma_f32_16x16x32_bf16(a0, bfr[0][kk], acc[0][0], 0, 0, 0);
            acc[0][1] = __builtin_amdgcn_mfma_f32_16x16x32_bf16(a0, bfr[1][kk], acc[0][1], 0, 0, 0);
            acc[1][0] = __builtin_amdgcn_mfma_f32_16x16x32_bf16(a1, bfr[0][kk], acc[1][0], 0, 0, 0);
            acc[1][1] = __builtin_amdgcn_mfma_f32_16x16x32_bf16(a1, bfr[1][kk], acc[1][1], 0, 0, 0);
        }

#pragma unroll
        for (int mr = 0; mr < 2; ++mr) {
            const int trow = t0 + wm * 32 + mr * 16 + lg * 4;
#pragma unroll
            for (int r = 0; r < 4; ++r) {
                const int t = trow + r;
                const float sxv = sx[t];
#pragma unroll
                for (int nr = 0; nr < 2; ++nr) {
                    const int n = n0 + wn * 32 + nr * 16 + lm;
                    if (n < N_COLS)
                        out[(size_t)t * N_COLS + n] =
                            acc[mr][nr][r] * ((sxv * swv[nr]) * invqq) + bv[nr];
                }
            }
        }
    }
}

extern "C" void kernel_launch(void* const* d_in, const int* in_sizes, int n_in,
                              void* d_out, int out_size, void* d_ws, size_t ws_size,
                              hipStream_t stream) {
    const float* X    = (const float*)d_in[0];   // [8,128,256] f32
    const float* W    = (const float*)d_in[1];   // [100000,256] f32
    const float* bias = (const float*)d_in[2];   // [100000] f32
    float* out = (float*)d_out;                  // [1024,100000] f32

    const size_t x8_bytes = (size_t)T_ROWS * H_DIM * 2;
    const size_t sx_bytes = (size_t)T_ROWS * 4;
    const size_t w8_bytes = (size_t)N_COLS * H_DIM * 2;
    const size_t sw_bytes = (size_t)N_COLS * 4;
    const size_t need = x8_bytes + sx_bytes + w8_bytes + sw_bytes;

    short* x8 = (short*)d_ws;
    float* sx = (float*)((char*)d_ws + x8_bytes);

    quant_x<<<T_ROWS / 4, 256, 0, stream>>>(X, x8, sx);

    if (ws_size >= need) {
        short* w8 = (short*)((char*)d_ws + x8_bytes + sx_bytes);
        float* sw = (float*)((char*)d_ws + x8_bytes + sx_bytes + w8_bytes);
        quant_w<<<N_COLS / 4, 256, 0, stream>>>(W, w8, sw);
        gemm_swap<<<GRID3, 256, 0, stream>>>(x8, sx, w8, sw, bias, out);
    } else {
        gemm_main<<<(N_COLS + 63) / 64, 256, 0, stream>>>(W, bias, x8, sx, out);
    }
}